// Round 11
// baseline (723.441 us; speedup 1.0000x reference)
//
#include <hip/hip_runtime.h>
#include <stdint.h>
#include <math.h>

#define N_NODES 50000
#define N_EDGES 800000
#define D 128
#define N_GRAPHS 16
#define ZP 264         // LDS z-tile row pitch in bf16 elems (264*2B=528B = 132 floats -> 16B-aligned rows)
#define PBLK 128       // nodes per pool block
#define PSL 16         // nodes per pool slice
#define SCAN_BLOCKS 196
#define CSR_CAP 1150400 // sum of 8-padded degrees <= 800000 + 7*50000
#define HB_ELEMS ((size_t)N_NODES * D)

typedef __attribute__((ext_vector_type(8))) short bf16x8;   // 8 bf16 (4 VGPRs)
typedef __attribute__((ext_vector_type(4))) float f32x4;

__device__ __forceinline__ float leaky(float y){ return y > 0.f ? y : 0.01f * y; }

// monotonic float->uint encoding for atomic max; 0 = "empty" marker
__device__ __forceinline__ unsigned fenc(float f){
    unsigned u = __float_as_uint(f);
    return (f >= 0.f) ? (u | 0x80000000u) : ~u;
}
__device__ __forceinline__ float fdec(unsigned e){
    return (e & 0x80000000u) ? __uint_as_float(e & 0x7fffffffu) : __uint_as_float(~e);
}

// bf16 pack/unpack (round-to-nearest-even)
__device__ __forceinline__ unsigned short f2bf(float f){
    unsigned u = __float_as_uint(f);
    u += 0x7fffu + ((u >> 16) & 1u);
    return (unsigned short)(u >> 16);
}
__device__ __forceinline__ unsigned pk2(float lo, float hi){
    return (unsigned)f2bf(lo) | ((unsigned)f2bf(hi) << 16);
}
__device__ __forceinline__ void maxbf8(float a[8], uint4 v){
    a[0] = fmaxf(a[0], __uint_as_float(v.x << 16)); a[1] = fmaxf(a[1], __uint_as_float(v.x & 0xffff0000u));
    a[2] = fmaxf(a[2], __uint_as_float(v.y << 16)); a[3] = fmaxf(a[3], __uint_as_float(v.y & 0xffff0000u));
    a[4] = fmaxf(a[4], __uint_as_float(v.z << 16)); a[5] = fmaxf(a[5], __uint_as_float(v.z & 0xffff0000u));
    a[6] = fmaxf(a[6], __uint_as_float(v.w << 16)); a[7] = fmaxf(a[7], __uint_as_float(v.w & 0xffff0000u));
}
__device__ __forceinline__ float4 max4(float4 a, float4 b){
    float4 r;
    r.x = fmaxf(a.x, b.x); r.y = fmaxf(a.y, b.y);
    r.z = fmaxf(a.z, b.z); r.w = fmaxf(a.w, b.w);
    return r;
}

// ---------------- combined pre-pass: hb=bf16(x), Wt transpose, zero deg/xg/bins ----------------
__global__ __launch_bounds__(256) void k_pre(const float* __restrict__ x, unsigned short* __restrict__ hb,
                                             const float* __restrict__ w0, const float* __restrict__ w1,
                                             const float* __restrict__ w2, const float* __restrict__ w3,
                                             unsigned short* __restrict__ Wt,
                                             int* __restrict__ deg, unsigned* __restrict__ xg,
                                             int* __restrict__ bins){
    int id = blockIdx.x * 256 + threadIdx.x;
    if (id < N_NODES * D / 4){
        float4 v = ((const float4*)x)[id];
        uint2 r; r.x = pk2(v.x, v.y); r.y = pk2(v.z, v.w);
        ((uint2*)hb)[id] = r;
    }
    if (id < 4 * D * 2 * D){
        int layer = id >> 15;
        int rem = id & 32767;
        int n = rem >> 8;
        int k = rem & 255;
        const float* w = (layer == 0) ? w0 : (layer == 1) ? w1 : (layer == 2) ? w2 : w3;
        Wt[id] = f2bf(w[(size_t)k * D + n]);
    }
    if (id < 50048) deg[id] = 0;
    if (id < N_GRAPHS * D) xg[id] = 0u;
    if (id < 256) bins[id] = 0;
}

// ---------------- f32 -> bf16 shadow convert (fallback path) ----------------
__global__ __launch_bounds__(256) void k_cvt(const float* __restrict__ src, unsigned short* __restrict__ dst){
    int id = blockIdx.x * 256 + threadIdx.x;
    if (id < N_NODES * D / 4){
        float4 v = ((const float4*)src)[id];
        uint2 r; r.x = pk2(v.x, v.y); r.y = pk2(v.z, v.w);
        ((uint2*)dst)[id] = r;
    }
}

// ---------------- CSR build (int4 reads, ushort entries, 8-aligned 8-padded segments) ----------------
__global__ __launch_bounds__(256) void k_hist(const int* __restrict__ dst, int* __restrict__ deg){
    int e4 = blockIdx.x * 256 + threadIdx.x;
    if (e4 < N_EDGES / 4){
        int4 d = ((const int4*)dst)[e4];
        atomicAdd(&deg[d.x], 1); atomicAdd(&deg[d.y], 1);
        atomicAdd(&deg[d.z], 1); atomicAdd(&deg[d.w], 1);
    }
}

__global__ __launch_bounds__(256) void k_scan1(const int* __restrict__ deg, int* __restrict__ bsum){
    __shared__ int sh[256];
    int i = blockIdx.x * 256 + threadIdx.x;
    int dv = (i < N_NODES) ? deg[i] : 0;
    sh[threadIdx.x] = (dv + 7) & ~7;               // 8-padded
    __syncthreads();
    for (int s = 128; s > 0; s >>= 1){
        if (threadIdx.x < s) sh[threadIdx.x] += sh[threadIdx.x + s];
        __syncthreads();
    }
    if (threadIdx.x == 0) bsum[blockIdx.x] = sh[0];
}

__global__ __launch_bounds__(256) void k_scan2(const int* __restrict__ bsum, int* __restrict__ bbase){
    __shared__ int sh[256];
    int t = threadIdx.x;
    int v = (t < SCAN_BLOCKS) ? bsum[t] : 0;
    sh[t] = v;
    __syncthreads();
    for (int d = 1; d < 256; d <<= 1){
        int tv = (t >= d) ? sh[t - d] : 0;
        __syncthreads();
        sh[t] += tv;
        __syncthreads();
    }
    if (t < SCAN_BLOCKS) bbase[t] = sh[t] - v;   // exclusive
}

__global__ __launch_bounds__(256) void k_scan3(const int* __restrict__ deg, const int* __restrict__ bbase,
                                               int* __restrict__ off, int* __restrict__ cursor){
    __shared__ int sh[256];
    int t = threadIdx.x;
    int i = blockIdx.x * 256 + t;
    int dv = (i < N_NODES) ? deg[i] : 0;
    int v = (dv + 7) & ~7;                        // 8-padded
    sh[t] = v;
    __syncthreads();
    for (int d = 1; d < 256; d <<= 1){
        int tv = (t >= d) ? sh[t - d] : 0;
        __syncthreads();
        sh[t] += tv;
        __syncthreads();
    }
    if (i < N_NODES){
        int e = bbase[blockIdx.x] + sh[t] - v;    // 8-aligned base
        off[i] = e;
        cursor[i] = e;
    }
}

__global__ __launch_bounds__(256) void k_fill(const int* __restrict__ src, const int* __restrict__ dst,
                                              int* __restrict__ cursor, unsigned short* __restrict__ csr16){
    int e4 = blockIdx.x * 256 + threadIdx.x;
    if (e4 < N_EDGES / 4){
        int4 d = ((const int4*)dst)[e4];
        int4 s = ((const int4*)src)[e4];
        int p;
        p = atomicAdd(&cursor[d.x], 1); csr16[p] = (unsigned short)s.x;
        p = atomicAdd(&cursor[d.y], 1); csr16[p] = (unsigned short)s.y;
        p = atomicAdd(&cursor[d.z], 1); csr16[p] = (unsigned short)s.z;
        p = atomicAdd(&cursor[d.w], 1); csr16[p] = (unsigned short)s.w;
    }
}

// pad each node's segment to a multiple of 8 by duplicating its first edge (max-invariant)
__global__ __launch_bounds__(256) void k_pad(const int* __restrict__ deg, const int* __restrict__ off,
                                             unsigned short* __restrict__ csr16){
    int i = blockIdx.x * 256 + threadIdx.x;
    if (i < N_NODES){
        int n = deg[i];
        if (n > 0){
            int base = off[i];
            unsigned short s0 = csr16[base];
            int n8 = (n + 7) & ~7;
            for (int j = n; j < n8; j++) csr16[base + j] = s0;
        }
    }
}

// ---------------- degree counting-sort: histogram, scan, scatter -> perm ----------------
__global__ __launch_bounds__(256) void k_dhist(const int* __restrict__ deg, int* __restrict__ bins){
    int i = blockIdx.x * 256 + threadIdx.x;
    if (i < N_NODES) atomicAdd(&bins[min(deg[i], 255)], 1);
}

__global__ __launch_bounds__(256) void k_dscan(const int* __restrict__ bins, int* __restrict__ bincur){
    __shared__ int sh[256];
    int t = threadIdx.x;
    int v = bins[t];
    sh[t] = v;
    __syncthreads();
    for (int d = 1; d < 256; d <<= 1){
        int tv = (t >= d) ? sh[t - d] : 0;
        __syncthreads();
        sh[t] += tv;
        __syncthreads();
    }
    bincur[t] = sh[t] - v;   // exclusive base
}

__global__ __launch_bounds__(256) void k_dscat(const int* __restrict__ deg, int* __restrict__ bincur,
                                               int* __restrict__ perm){
    int i = blockIdx.x * 256 + threadIdx.x;
    if (i < N_NODES){
        int b = min(deg[i], 255);
        int p = atomicAdd(&bincur[b], 1);
        perm[p] = i;
    }
}

// ---------------- fused step: perm'd gather + MFMA GEMM + coalesced f32/bf16 epilogue ------
// block = 64 nodes (perm[nb..nb+63], degree-uniform), 512 threads (8 waves).
__global__ __launch_bounds__(512, 8) void k_step(const float* __restrict__ hin,
                                              const unsigned short* __restrict__ hb,
                                              const unsigned short* __restrict__ csr16,
                                              const int* __restrict__ deg, const int* __restrict__ off,
                                              const int* __restrict__ perm,
                                              const unsigned short* __restrict__ Wt, const float* __restrict__ b,
                                              float* __restrict__ hout, unsigned short* __restrict__ hbout,
                                              int add_skip, int write_hb){
    __shared__ unsigned short zt[64 * ZP];
    __shared__ int pn[64];
    int tid = threadIdx.x;
    int nb = blockIdx.x * 64;
    int lane = tid & 63;
    int wv = tid >> 6;                    // 0..7

    if (tid < 64){
        int idx = nb + tid;
        pn[tid] = (idx < N_NODES) ? perm[idx] : -1;
    }
    __syncthreads();

    // stage h-half (256B contiguous per row): 1024 slots, 512 threads x 2
    #pragma unroll
    for (int j = 0; j < 2; j++){
        int idx = j * 512 + tid;          // 0..1023
        int row = idx >> 4;               // 0..63
        int ch  = idx & 15;               // 16B chunk -> feats ch*8..+7
        int node = pn[row];
        uint4 v = make_uint4(0u, 0u, 0u, 0u);
        if (node >= 0) v = *(const uint4*)&hb[(size_t)node * D + ch * 8];
        *(uint4*)&zt[row * ZP + ch * 8] = v;
    }

    // gather-max: 32 16-lane groups, 2 nodes each (serial passes), MLP=8, tail-free (8-padded CSR)
    {
        int group = tid >> 4;             // 0..31
        int chunk = tid & 15;             // feats chunk*8..+7
        #pragma unroll
        for (int g = 0; g < 2; g++){
            int ml = group + g * 32;      // local node 0..63
            int node = pn[ml];
            int n = 0, base = 0;
            if (node >= 0){ n = deg[node]; base = off[node]; }
            const float NEG = -INFINITY;
            float a[8] = {NEG, NEG, NEG, NEG, NEG, NEG, NEG, NEG};
            int n8 = (n + 7) & ~7;        // 0 when n==0
            for (int i = 0; i < n8; i += 8){
                uint4 ss = *(const uint4*)&csr16[base + i];   // 8 edge ids, 16B-aligned
                int s0 = ss.x & 0xffff, s1 = ss.x >> 16;
                int s2 = ss.y & 0xffff, s3 = ss.y >> 16;
                int s4 = ss.z & 0xffff, s5 = ss.z >> 16;
                int s6 = ss.w & 0xffff, s7 = ss.w >> 16;
                uint4 v0 = *(const uint4*)&hb[(size_t)s0 * D + chunk * 8];
                uint4 v1 = *(const uint4*)&hb[(size_t)s1 * D + chunk * 8];
                uint4 v2 = *(const uint4*)&hb[(size_t)s2 * D + chunk * 8];
                uint4 v3 = *(const uint4*)&hb[(size_t)s3 * D + chunk * 8];
                uint4 v4 = *(const uint4*)&hb[(size_t)s4 * D + chunk * 8];
                uint4 v5 = *(const uint4*)&hb[(size_t)s5 * D + chunk * 8];
                uint4 v6 = *(const uint4*)&hb[(size_t)s6 * D + chunk * 8];
                uint4 v7 = *(const uint4*)&hb[(size_t)s7 * D + chunk * 8];
                maxbf8(a, v0); maxbf8(a, v1); maxbf8(a, v2); maxbf8(a, v3);
                maxbf8(a, v4); maxbf8(a, v5); maxbf8(a, v6); maxbf8(a, v7);
            }
            uint4 r;
            if (n == 0){
                r = make_uint4(0u, 0u, 0u, 0u);
            } else {
                r.x = pk2(a[0], a[1]); r.y = pk2(a[2], a[3]);
                r.z = pk2(a[4], a[5]); r.w = pk2(a[6], a[7]);
            }
            *(uint4*)&zt[ml * ZP + D + chunk * 8] = r;
        }
    }
    __syncthreads();

    // MFMA: wave w -> nodes (w&3)*16..+15, output-half (w>>2)*64..+63
    int col = lane & 15;
    int quad = lane >> 4;
    int mg = wv & 3;
    int og = wv >> 2;
    int m0 = mg * 16;
    int f0 = og * 64;

    f32x4 acc[4];
    #pragma unroll
    for (int nt = 0; nt < 4; nt++) acc[nt] = (f32x4){0.f, 0.f, 0.f, 0.f};

    const unsigned short* zrow = &zt[(m0 + col) * ZP + quad * 8];
    const unsigned short* wrow = &Wt[(size_t)(f0 + col) * 256 + quad * 8];

    #pragma unroll
    for (int ks = 0; ks < 8; ks++){
        bf16x8 afrag = *(const bf16x8*)&zrow[ks * 32];
        #pragma unroll
        for (int nt = 0; nt < 4; nt++){
            bf16x8 bfrag = *(const bf16x8*)&wrow[nt * 16 * 256 + ks * 32];
            acc[nt] = __builtin_amdgcn_mfma_f32_16x16x32_bf16(afrag, bfrag, acc[nt], 0, 0, 0);
        }
    }

    __syncthreads();   // all waves done reading zt (A-frags)

    // write y = leaky(acc + b) into zt as f32 (pitch 132 floats = 528 B)
    float* zf = (float*)zt;
    #pragma unroll
    for (int nt = 0; nt < 4; nt++){
        int feat = f0 + nt * 16 + col;
        float bb_ = b[feat];
        #pragma unroll
        for (int r = 0; r < 4; r++){
            int row = m0 + quad * 4 + r;
            zf[row * 132 + feat] = leaky(acc[nt][r] + bb_);
        }
    }
    __syncthreads();

    // coalesced epilogue (512B contiguous per row): float4 skip-load + float4 h-store + ushort4 hb-store
    #pragma unroll
    for (int j = 0; j < 4; j++){
        int idx = j * 512 + tid;          // 0..2047 float4 slots
        int row = idx >> 5;               // 0..63
        int q = idx & 31;                 // feats 4q..4q+3
        int node = pn[row];
        if (node >= 0){
            float4 y = *(float4*)&zf[row * 132 + 4 * q];
            if (add_skip){
                float4 hv = *(const float4*)&hin[(size_t)node * D + 4 * q];
                y.x += hv.x; y.y += hv.y; y.z += hv.z; y.w += hv.w;
            }
            *(float4*)&hout[(size_t)node * D + 4 * q] = y;
            if (write_hb){
                ushort4 rb;
                rb.x = f2bf(y.x); rb.y = f2bf(y.y); rb.z = f2bf(y.z); rb.w = f2bf(y.w);
                *(ushort4*)&hbout[(size_t)node * D + 4 * q] = rb;
            }
        }
    }
}

// ---------------- global max-pool per graph (batch sorted, int32) ----------------
__global__ __launch_bounds__(256) void k_pool(const float* __restrict__ h, const int* __restrict__ batch,
                                              unsigned* __restrict__ xg){
    __shared__ unsigned lmax[2 * D];
    int tid = threadIdx.x;
    lmax[tid] = 0u;
    __syncthreads();

    int n0 = blockIdx.x * PBLK;
    int g0 = batch[n0];
    int q = tid & 31;
    int s = tid >> 5;
    int i0 = n0 + s * PSL;
    int i1 = min(i0 + PSL, N_NODES);

    if (i0 < N_NODES){
        const float NEG = -INFINITY;
        float4 m = make_float4(NEG, NEG, NEG, NEG);
        int curg = batch[i0];
        int i = i0;
        for (; i + 2 <= i1; i += 2){
            int ga = batch[i];
            int gb = batch[i + 1];
            float4 va = *(const float4*)&h[(size_t)i * D + 4 * q];
            float4 vb = *(const float4*)&h[(size_t)(i + 1) * D + 4 * q];
            if (ga != curg){
                int rel = curg - g0;
                unsigned* dst = (rel < 2) ? &lmax[rel * D + 4 * q] : &xg[curg * D + 4 * q];
                atomicMax(dst + 0, fenc(m.x)); atomicMax(dst + 1, fenc(m.y));
                atomicMax(dst + 2, fenc(m.z)); atomicMax(dst + 3, fenc(m.w));
                curg = ga; m = make_float4(NEG, NEG, NEG, NEG);
            }
            m = max4(m, va);
            if (gb != curg){
                int rel = curg - g0;
                unsigned* dst = (rel < 2) ? &lmax[rel * D + 4 * q] : &xg[curg * D + 4 * q];
                atomicMax(dst + 0, fenc(m.x)); atomicMax(dst + 1, fenc(m.y));
                atomicMax(dst + 2, fenc(m.z)); atomicMax(dst + 3, fenc(m.w));
                curg = gb; m = make_float4(NEG, NEG, NEG, NEG);
            }
            m = max4(m, vb);
        }
        if (i < i1){
            int ga = batch[i];
            float4 va = *(const float4*)&h[(size_t)i * D + 4 * q];
            if (ga != curg){
                int rel = curg - g0;
                unsigned* dst = (rel < 2) ? &lmax[rel * D + 4 * q] : &xg[curg * D + 4 * q];
                atomicMax(dst + 0, fenc(m.x)); atomicMax(dst + 1, fenc(m.y));
                atomicMax(dst + 2, fenc(m.z)); atomicMax(dst + 3, fenc(m.w));
                curg = ga; m = make_float4(NEG, NEG, NEG, NEG);
            }
            m = max4(m, va);
        }
        {
            int rel = curg - g0;
            unsigned* dst = (rel < 2) ? &lmax[rel * D + 4 * q] : &xg[curg * D + 4 * q];
            atomicMax(dst + 0, fenc(m.x)); atomicMax(dst + 1, fenc(m.y));
            atomicMax(dst + 2, fenc(m.z)); atomicMax(dst + 3, fenc(m.w));
        }
    }
    __syncthreads();

    if (tid < D){
        unsigned e = lmax[tid];
        if (e) atomicMax(&xg[g0 * D + tid], e);
    } else {
        int f = tid - D;
        int g1 = g0 + 1;
        if (g1 < N_GRAPHS){
            unsigned e = lmax[D + f];
            if (e) atomicMax(&xg[g1 * D + f], e);
        }
    }
}

// ---------------- head: leaky(xg @ wg[:128] + bg) ----------------
__global__ __launch_bounds__(256) void k_final(const unsigned* __restrict__ xg_enc, const float* __restrict__ wg,
                                               const float* __restrict__ bg, float* __restrict__ out){
    __shared__ float xs[N_GRAPHS * D];
    int tid = threadIdx.x;
    for (int i = tid; i < N_GRAPHS * D; i += 256){
        unsigned e = xg_enc[i];
        xs[i] = (e == 0u) ? 0.f : fdec(e);
    }
    __syncthreads();
    int g = tid >> 4;
    int j0 = (tid & 15) * 8;
    float acc[8];
    #pragma unroll
    for (int j = 0; j < 8; j++) acc[j] = 0.f;
    for (int k = 0; k < D; k++){
        float xv = xs[g * D + k];
        const float* wr = &wg[(size_t)k * D + j0];
        #pragma unroll
        for (int j = 0; j < 8; j++) acc[j] = fmaf(xv, wr[j], acc[j]);
    }
    float* orow = &out[(size_t)N_NODES * D + g * D + j0];
    #pragma unroll
    for (int j = 0; j < 8; j++) orow[j] = leaky(acc[j] + bg[j0 + j]);
}

extern "C" void kernel_launch(void* const* d_in, const int* in_sizes, int n_in,
                              void* d_out, int out_size, void* d_ws, size_t ws_size,
                              hipStream_t stream){
    const float* x = (const float*)d_in[0];
    const int* eidx  = (const int*)d_in[1];   // harness converts integer inputs to int32
    const int* batch = (const int*)d_in[2];
    const float* w[4]  = {(const float*)d_in[4], (const float*)d_in[6], (const float*)d_in[8], (const float*)d_in[10]};
    const float* bb[4] = {(const float*)d_in[5], (const float*)d_in[7], (const float*)d_in[9], (const float*)d_in[11]};
    const float* wg = (const float*)d_in[12];
    const float* bg = (const float*)d_in[13];
    const int* esrc = eidx;
    const int* edst = eidx + N_EDGES;

    // workspace layout: base ~3.6 MB + hb0 12.8 MB (+ hb1 12.8 MB if ws allows ping-pong)
    char* ws = (char*)d_ws;
    int* deg    = (int*)ws;       ws += 50048 * 4;
    int* off    = (int*)ws;       ws += 50048 * 4;
    int* cursor = (int*)ws;       ws += 50048 * 4;
    int* perm   = (int*)ws;       ws += 50048 * 4;
    int* bsum   = (int*)ws;       ws += 256 * 4;
    int* bbase  = (int*)ws;       ws += 256 * 4;
    int* bins   = (int*)ws;       ws += 256 * 4;
    int* bincur = (int*)ws;       ws += 256 * 4;
    unsigned* xg_enc = (unsigned*)ws; ws += N_GRAPHS * D * 4;
    unsigned short* Wt = (unsigned short*)ws; ws += 4 * 2 * D * D * 2;  // 4 layers, [n][k] bf16
    unsigned short* csr16 = (unsigned short*)ws; ws += CSR_CAP * 2;
    unsigned short* hb0 = (unsigned short*)(((uintptr_t)ws + 255) & ~(uintptr_t)255);
    unsigned short* hb1 = hb0 + HB_ELEMS;
    size_t need_pp = (size_t)((char*)(hb1 + HB_ELEMS) - (char*)d_ws);
    int pp = (ws_size >= need_pp);     // ping-pong shadow if workspace allows (deterministic per run)
    float* h = (float*)d_out;          // f32 h lives in the output buffer (fully written by step 0)

    k_pre  <<<6250, 256, 0, stream>>>(x, hb0, w[0], w[1], w[2], w[3], Wt, deg, xg_enc, bins);
    k_hist <<<(N_EDGES / 4 + 255) / 256, 256, 0, stream>>>(edst, deg);
    k_scan1<<<SCAN_BLOCKS, 256, 0, stream>>>(deg, bsum);
    k_scan2<<<1, 256, 0, stream>>>(bsum, bbase);
    k_scan3<<<SCAN_BLOCKS, 256, 0, stream>>>(deg, bbase, off, cursor);
    k_fill <<<(N_EDGES / 4 + 255) / 256, 256, 0, stream>>>(esrc, edst, cursor, csr16);
    k_pad  <<<SCAN_BLOCKS, 256, 0, stream>>>(deg, off, csr16);
    k_dhist<<<SCAN_BLOCKS, 256, 0, stream>>>(deg, bins);
    k_dscan<<<1, 256, 0, stream>>>(bins, bincur);
    k_dscat<<<SCAN_BLOCKS, 256, 0, stream>>>(deg, bincur, perm);

    unsigned short* cur = hb0;
    unsigned short* nxt = pp ? hb1 : hb0;
    for (int s = 0; s < 4; s++){
        int wb = pp && (s < 3);        // ping-pong: write next shadow in-kernel (separate buffer)
        k_step<<<(N_NODES + 63) / 64, 512, 0, stream>>>(h, cur, csr16, deg, off, perm,
                                                        Wt + (size_t)s * 2 * D * D, bb[s], h, nxt,
                                                        s > 0, wb);
        if (!pp && s < 3)              // fallback: refresh single shadow in a separate launch
            k_cvt<<<6250, 256, 0, stream>>>(h, hb0);
        if (pp){ unsigned short* t = cur; cur = nxt; nxt = t; }
    }

    k_pool <<<(N_NODES + PBLK - 1) / PBLK, 256, 0, stream>>>(h, batch, xg_enc);
    k_final<<<1, 256, 0, stream>>>(xg_enc, wg, bg, (float*)d_out);
}

// Round 12
// 464.792 us; speedup vs baseline: 1.5565x; 1.5565x over previous
//
#include <hip/hip_runtime.h>
#include <stdint.h>
#include <math.h>

#define N_NODES 50000
#define N_EDGES 800000
#define D 128
#define N_GRAPHS 16
#define ZP 264         // LDS z-tile row pitch in bf16 elems (264*2B=528B = 132 floats -> 16B-aligned rows)
#define PBLK 128       // nodes per pool block
#define PSL 16         // nodes per pool slice
#define SCAN_BLOCKS 196
#define CSR_CAP 1150400 // sum of 8-padded degrees <= 800000 + 7*50000
#define HB_ELEMS ((size_t)N_NODES * D)

typedef __attribute__((ext_vector_type(8))) short bf16x8;   // 8 bf16 (4 VGPRs)
typedef __attribute__((ext_vector_type(4))) float f32x4;

__device__ __forceinline__ float leaky(float y){ return y > 0.f ? y : 0.01f * y; }

// monotonic float->uint encoding for atomic max; 0 = "empty" marker
__device__ __forceinline__ unsigned fenc(float f){
    unsigned u = __float_as_uint(f);
    return (f >= 0.f) ? (u | 0x80000000u) : ~u;
}
__device__ __forceinline__ float fdec(unsigned e){
    return (e & 0x80000000u) ? __uint_as_float(e & 0x7fffffffu) : __uint_as_float(~e);
}

// bf16 pack/unpack (round-to-nearest-even)
__device__ __forceinline__ unsigned short f2bf(float f){
    unsigned u = __float_as_uint(f);
    u += 0x7fffu + ((u >> 16) & 1u);
    return (unsigned short)(u >> 16);
}
__device__ __forceinline__ unsigned pk2(float lo, float hi){
    return (unsigned)f2bf(lo) | ((unsigned)f2bf(hi) << 16);
}
__device__ __forceinline__ void maxbf8(float a[8], uint4 v){
    a[0] = fmaxf(a[0], __uint_as_float(v.x << 16)); a[1] = fmaxf(a[1], __uint_as_float(v.x & 0xffff0000u));
    a[2] = fmaxf(a[2], __uint_as_float(v.y << 16)); a[3] = fmaxf(a[3], __uint_as_float(v.y & 0xffff0000u));
    a[4] = fmaxf(a[4], __uint_as_float(v.z << 16)); a[5] = fmaxf(a[5], __uint_as_float(v.z & 0xffff0000u));
    a[6] = fmaxf(a[6], __uint_as_float(v.w << 16)); a[7] = fmaxf(a[7], __uint_as_float(v.w & 0xffff0000u));
}
__device__ __forceinline__ float4 max4(float4 a, float4 b){
    float4 r;
    r.x = fmaxf(a.x, b.x); r.y = fmaxf(a.y, b.y);
    r.z = fmaxf(a.z, b.z); r.w = fmaxf(a.w, b.w);
    return r;
}

// ---------------- combined pre-pass: hb=bf16(x), Wt transpose, zero deg/xg/bins ----------------
__global__ __launch_bounds__(256) void k_pre(const float* __restrict__ x, unsigned short* __restrict__ hb,
                                             const float* __restrict__ w0, const float* __restrict__ w1,
                                             const float* __restrict__ w2, const float* __restrict__ w3,
                                             unsigned short* __restrict__ Wt,
                                             int* __restrict__ deg, unsigned* __restrict__ xg,
                                             int* __restrict__ bins){
    int id = blockIdx.x * 256 + threadIdx.x;
    if (id < N_NODES * D / 4){
        float4 v = ((const float4*)x)[id];
        uint2 r; r.x = pk2(v.x, v.y); r.y = pk2(v.z, v.w);
        ((uint2*)hb)[id] = r;
    }
    if (id < 4 * D * 2 * D){
        int layer = id >> 15;
        int rem = id & 32767;
        int n = rem >> 8;
        int k = rem & 255;
        const float* w = (layer == 0) ? w0 : (layer == 1) ? w1 : (layer == 2) ? w2 : w3;
        Wt[id] = f2bf(w[(size_t)k * D + n]);
    }
    if (id < 50048) deg[id] = 0;
    if (id < N_GRAPHS * D) xg[id] = 0u;
    if (id < 256) bins[id] = 0;
}

// ---------------- f32 -> bf16 shadow convert (fallback path) ----------------
__global__ __launch_bounds__(256) void k_cvt(const float* __restrict__ src, unsigned short* __restrict__ dst){
    int id = blockIdx.x * 256 + threadIdx.x;
    if (id < N_NODES * D / 4){
        float4 v = ((const float4*)src)[id];
        uint2 r; r.x = pk2(v.x, v.y); r.y = pk2(v.z, v.w);
        ((uint2*)dst)[id] = r;
    }
}

// ---------------- CSR build (int4 reads, ushort entries, 8-aligned 8-padded segments) ----------------
__global__ __launch_bounds__(256) void k_hist(const int* __restrict__ dst, int* __restrict__ deg){
    int e4 = blockIdx.x * 256 + threadIdx.x;
    if (e4 < N_EDGES / 4){
        int4 d = ((const int4*)dst)[e4];
        atomicAdd(&deg[d.x], 1); atomicAdd(&deg[d.y], 1);
        atomicAdd(&deg[d.z], 1); atomicAdd(&deg[d.w], 1);
    }
}

__global__ __launch_bounds__(256) void k_scan1(const int* __restrict__ deg, int* __restrict__ bsum){
    __shared__ int sh[256];
    int i = blockIdx.x * 256 + threadIdx.x;
    int dv = (i < N_NODES) ? deg[i] : 0;
    sh[threadIdx.x] = (dv + 7) & ~7;               // 8-padded
    __syncthreads();
    for (int s = 128; s > 0; s >>= 1){
        if (threadIdx.x < s) sh[threadIdx.x] += sh[threadIdx.x + s];
        __syncthreads();
    }
    if (threadIdx.x == 0) bsum[blockIdx.x] = sh[0];
}

__global__ __launch_bounds__(256) void k_scan2(const int* __restrict__ bsum, int* __restrict__ bbase){
    __shared__ int sh[256];
    int t = threadIdx.x;
    int v = (t < SCAN_BLOCKS) ? bsum[t] : 0;
    sh[t] = v;
    __syncthreads();
    for (int d = 1; d < 256; d <<= 1){
        int tv = (t >= d) ? sh[t - d] : 0;
        __syncthreads();
        sh[t] += tv;
        __syncthreads();
    }
    if (t < SCAN_BLOCKS) bbase[t] = sh[t] - v;   // exclusive
}

__global__ __launch_bounds__(256) void k_scan3(const int* __restrict__ deg, const int* __restrict__ bbase,
                                               int* __restrict__ off, int* __restrict__ cursor){
    __shared__ int sh[256];
    int t = threadIdx.x;
    int i = blockIdx.x * 256 + t;
    int dv = (i < N_NODES) ? deg[i] : 0;
    int v = (dv + 7) & ~7;                        // 8-padded
    sh[t] = v;
    __syncthreads();
    for (int d = 1; d < 256; d <<= 1){
        int tv = (t >= d) ? sh[t - d] : 0;
        __syncthreads();
        sh[t] += tv;
        __syncthreads();
    }
    if (i < N_NODES){
        int e = bbase[blockIdx.x] + sh[t] - v;    // 8-aligned base
        off[i] = e;
        cursor[i] = e;
    }
}

__global__ __launch_bounds__(256) void k_fill(const int* __restrict__ src, const int* __restrict__ dst,
                                              int* __restrict__ cursor, unsigned short* __restrict__ csr16){
    int e4 = blockIdx.x * 256 + threadIdx.x;
    if (e4 < N_EDGES / 4){
        int4 d = ((const int4*)dst)[e4];
        int4 s = ((const int4*)src)[e4];
        int p;
        p = atomicAdd(&cursor[d.x], 1); csr16[p] = (unsigned short)s.x;
        p = atomicAdd(&cursor[d.y], 1); csr16[p] = (unsigned short)s.y;
        p = atomicAdd(&cursor[d.z], 1); csr16[p] = (unsigned short)s.z;
        p = atomicAdd(&cursor[d.w], 1); csr16[p] = (unsigned short)s.w;
    }
}

// pad each node's segment to a multiple of 8 by duplicating its first edge (max-invariant)
__global__ __launch_bounds__(256) void k_pad(const int* __restrict__ deg, const int* __restrict__ off,
                                             unsigned short* __restrict__ csr16){
    int i = blockIdx.x * 256 + threadIdx.x;
    if (i < N_NODES){
        int n = deg[i];
        if (n > 0){
            int base = off[i];
            unsigned short s0 = csr16[base];
            int n8 = (n + 7) & ~7;
            for (int j = n; j < n8; j++) csr16[base + j] = s0;
        }
    }
}

// ---------------- degree counting-sort (LDS pre-aggregated; Guideline 12) ----------------
__global__ __launch_bounds__(256) void k_dhist(const int* __restrict__ deg, int* __restrict__ bins){
    __shared__ int lb[256];
    int t = threadIdx.x;
    lb[t] = 0;
    __syncthreads();
    int i = blockIdx.x * 256 + t;
    if (i < N_NODES) atomicAdd(&lb[min(deg[i], 255)], 1);
    __syncthreads();
    int c = lb[t];
    if (c > 0) atomicAdd(&bins[t], c);
}

__global__ __launch_bounds__(256) void k_dscan(const int* __restrict__ bins, int* __restrict__ bincur){
    __shared__ int sh[256];
    int t = threadIdx.x;
    int v = bins[t];
    sh[t] = v;
    __syncthreads();
    for (int d = 1; d < 256; d <<= 1){
        int tv = (t >= d) ? sh[t - d] : 0;
        __syncthreads();
        sh[t] += tv;
        __syncthreads();
    }
    bincur[t] = sh[t] - v;   // exclusive base
}

// LDS local ranks + one global atomic per populated bin per block; non-stable but valid permutation
__global__ __launch_bounds__(256) void k_dscat(const int* __restrict__ deg, int* __restrict__ bincur,
                                               int* __restrict__ perm){
    __shared__ int lb[256];
    __shared__ int gbase[256];
    int t = threadIdx.x;
    lb[t] = 0;
    __syncthreads();
    int i = blockIdx.x * 256 + t;
    int b = 0, lrank = 0;
    if (i < N_NODES){
        b = min(deg[i], 255);
        lrank = atomicAdd(&lb[b], 1);
    }
    __syncthreads();
    int c = lb[t];
    if (c > 0) gbase[t] = atomicAdd(&bincur[t], c);
    __syncthreads();
    if (i < N_NODES) perm[gbase[b] + lrank] = i;
}

// ---------------- fused step: perm'd gather + MFMA GEMM + coalesced f32/bf16 epilogue ------
// block = 64 nodes (perm[nb..nb+63], degree-uniform), 512 threads (8 waves).
__global__ __launch_bounds__(512, 8) void k_step(const float* __restrict__ hin,
                                              const unsigned short* __restrict__ hb,
                                              const unsigned short* __restrict__ csr16,
                                              const int* __restrict__ deg, const int* __restrict__ off,
                                              const int* __restrict__ perm,
                                              const unsigned short* __restrict__ Wt, const float* __restrict__ b,
                                              float* __restrict__ hout, unsigned short* __restrict__ hbout,
                                              int add_skip, int write_hb){
    __shared__ unsigned short zt[64 * ZP];
    __shared__ int pn[64];
    int tid = threadIdx.x;
    int nb = blockIdx.x * 64;
    int lane = tid & 63;
    int wv = tid >> 6;                    // 0..7

    if (tid < 64){
        int idx = nb + tid;
        pn[tid] = (idx < N_NODES) ? perm[idx] : -1;
    }
    __syncthreads();

    // stage h-half (256B contiguous per row): 1024 slots, 512 threads x 2
    #pragma unroll
    for (int j = 0; j < 2; j++){
        int idx = j * 512 + tid;          // 0..1023
        int row = idx >> 4;               // 0..63
        int ch  = idx & 15;               // 16B chunk -> feats ch*8..+7
        int node = pn[row];
        uint4 v = make_uint4(0u, 0u, 0u, 0u);
        if (node >= 0) v = *(const uint4*)&hb[(size_t)node * D + ch * 8];
        *(uint4*)&zt[row * ZP + ch * 8] = v;
    }

    // gather-max: 32 16-lane groups, 2 nodes each (serial passes), MLP=8, tail-free (8-padded CSR)
    {
        int group = tid >> 4;             // 0..31
        int chunk = tid & 15;             // feats chunk*8..+7
        #pragma unroll
        for (int g = 0; g < 2; g++){
            int ml = group + g * 32;      // local node 0..63
            int node = pn[ml];
            int n = 0, base = 0;
            if (node >= 0){ n = deg[node]; base = off[node]; }
            const float NEG = -INFINITY;
            float a[8] = {NEG, NEG, NEG, NEG, NEG, NEG, NEG, NEG};
            int n8 = (n + 7) & ~7;        // 0 when n==0
            for (int i = 0; i < n8; i += 8){
                uint4 ss = *(const uint4*)&csr16[base + i];   // 8 edge ids, 16B-aligned
                int s0 = ss.x & 0xffff, s1 = ss.x >> 16;
                int s2 = ss.y & 0xffff, s3 = ss.y >> 16;
                int s4 = ss.z & 0xffff, s5 = ss.z >> 16;
                int s6 = ss.w & 0xffff, s7 = ss.w >> 16;
                uint4 v0 = *(const uint4*)&hb[(size_t)s0 * D + chunk * 8];
                uint4 v1 = *(const uint4*)&hb[(size_t)s1 * D + chunk * 8];
                uint4 v2 = *(const uint4*)&hb[(size_t)s2 * D + chunk * 8];
                uint4 v3 = *(const uint4*)&hb[(size_t)s3 * D + chunk * 8];
                uint4 v4 = *(const uint4*)&hb[(size_t)s4 * D + chunk * 8];
                uint4 v5 = *(const uint4*)&hb[(size_t)s5 * D + chunk * 8];
                uint4 v6 = *(const uint4*)&hb[(size_t)s6 * D + chunk * 8];
                uint4 v7 = *(const uint4*)&hb[(size_t)s7 * D + chunk * 8];
                maxbf8(a, v0); maxbf8(a, v1); maxbf8(a, v2); maxbf8(a, v3);
                maxbf8(a, v4); maxbf8(a, v5); maxbf8(a, v6); maxbf8(a, v7);
            }
            uint4 r;
            if (n == 0){
                r = make_uint4(0u, 0u, 0u, 0u);
            } else {
                r.x = pk2(a[0], a[1]); r.y = pk2(a[2], a[3]);
                r.z = pk2(a[4], a[5]); r.w = pk2(a[6], a[7]);
            }
            *(uint4*)&zt[ml * ZP + D + chunk * 8] = r;
        }
    }
    __syncthreads();

    // MFMA: wave w -> nodes (w&3)*16..+15, output-half (w>>2)*64..+63
    int col = lane & 15;
    int quad = lane >> 4;
    int mg = wv & 3;
    int og = wv >> 2;
    int m0 = mg * 16;
    int f0 = og * 64;

    f32x4 acc[4];
    #pragma unroll
    for (int nt = 0; nt < 4; nt++) acc[nt] = (f32x4){0.f, 0.f, 0.f, 0.f};

    const unsigned short* zrow = &zt[(m0 + col) * ZP + quad * 8];
    const unsigned short* wrow = &Wt[(size_t)(f0 + col) * 256 + quad * 8];

    #pragma unroll
    for (int ks = 0; ks < 8; ks++){
        bf16x8 afrag = *(const bf16x8*)&zrow[ks * 32];
        #pragma unroll
        for (int nt = 0; nt < 4; nt++){
            bf16x8 bfrag = *(const bf16x8*)&wrow[nt * 16 * 256 + ks * 32];
            acc[nt] = __builtin_amdgcn_mfma_f32_16x16x32_bf16(afrag, bfrag, acc[nt], 0, 0, 0);
        }
    }

    __syncthreads();   // all waves done reading zt (A-frags)

    // write y = leaky(acc + b) into zt as f32 (pitch 132 floats = 528 B)
    float* zf = (float*)zt;
    #pragma unroll
    for (int nt = 0; nt < 4; nt++){
        int feat = f0 + nt * 16 + col;
        float bb_ = b[feat];
        #pragma unroll
        for (int r = 0; r < 4; r++){
            int row = m0 + quad * 4 + r;
            zf[row * 132 + feat] = leaky(acc[nt][r] + bb_);
        }
    }
    __syncthreads();

    // coalesced epilogue (512B contiguous per row): float4 skip-load + float4 h-store + ushort4 hb-store
    #pragma unroll
    for (int j = 0; j < 4; j++){
        int idx = j * 512 + tid;          // 0..2047 float4 slots
        int row = idx >> 5;               // 0..63
        int q = idx & 31;                 // feats 4q..4q+3
        int node = pn[row];
        if (node >= 0){
            float4 y = *(float4*)&zf[row * 132 + 4 * q];
            if (add_skip){
                float4 hv = *(const float4*)&hin[(size_t)node * D + 4 * q];
                y.x += hv.x; y.y += hv.y; y.z += hv.z; y.w += hv.w;
            }
            *(float4*)&hout[(size_t)node * D + 4 * q] = y;
            if (write_hb){
                ushort4 rb;
                rb.x = f2bf(y.x); rb.y = f2bf(y.y); rb.z = f2bf(y.z); rb.w = f2bf(y.w);
                *(ushort4*)&hbout[(size_t)node * D + 4 * q] = rb;
            }
        }
    }
}

// ---------------- global max-pool per graph (batch sorted, int32) ----------------
__global__ __launch_bounds__(256) void k_pool(const float* __restrict__ h, const int* __restrict__ batch,
                                              unsigned* __restrict__ xg){
    __shared__ unsigned lmax[2 * D];
    int tid = threadIdx.x;
    lmax[tid] = 0u;
    __syncthreads();

    int n0 = blockIdx.x * PBLK;
    int g0 = batch[n0];
    int q = tid & 31;
    int s = tid >> 5;
    int i0 = n0 + s * PSL;
    int i1 = min(i0 + PSL, N_NODES);

    if (i0 < N_NODES){
        const float NEG = -INFINITY;
        float4 m = make_float4(NEG, NEG, NEG, NEG);
        int curg = batch[i0];
        int i = i0;
        for (; i + 2 <= i1; i += 2){
            int ga = batch[i];
            int gb = batch[i + 1];
            float4 va = *(const float4*)&h[(size_t)i * D + 4 * q];
            float4 vb = *(const float4*)&h[(size_t)(i + 1) * D + 4 * q];
            if (ga != curg){
                int rel = curg - g0;
                unsigned* dst = (rel < 2) ? &lmax[rel * D + 4 * q] : &xg[curg * D + 4 * q];
                atomicMax(dst + 0, fenc(m.x)); atomicMax(dst + 1, fenc(m.y));
                atomicMax(dst + 2, fenc(m.z)); atomicMax(dst + 3, fenc(m.w));
                curg = ga; m = make_float4(NEG, NEG, NEG, NEG);
            }
            m = max4(m, va);
            if (gb != curg){
                int rel = curg - g0;
                unsigned* dst = (rel < 2) ? &lmax[rel * D + 4 * q] : &xg[curg * D + 4 * q];
                atomicMax(dst + 0, fenc(m.x)); atomicMax(dst + 1, fenc(m.y));
                atomicMax(dst + 2, fenc(m.z)); atomicMax(dst + 3, fenc(m.w));
                curg = gb; m = make_float4(NEG, NEG, NEG, NEG);
            }
            m = max4(m, vb);
        }
        if (i < i1){
            int ga = batch[i];
            float4 va = *(const float4*)&h[(size_t)i * D + 4 * q];
            if (ga != curg){
                int rel = curg - g0;
                unsigned* dst = (rel < 2) ? &lmax[rel * D + 4 * q] : &xg[curg * D + 4 * q];
                atomicMax(dst + 0, fenc(m.x)); atomicMax(dst + 1, fenc(m.y));
                atomicMax(dst + 2, fenc(m.z)); atomicMax(dst + 3, fenc(m.w));
                curg = ga; m = make_float4(NEG, NEG, NEG, NEG);
            }
            m = max4(m, va);
        }
        {
            int rel = curg - g0;
            unsigned* dst = (rel < 2) ? &lmax[rel * D + 4 * q] : &xg[curg * D + 4 * q];
            atomicMax(dst + 0, fenc(m.x)); atomicMax(dst + 1, fenc(m.y));
            atomicMax(dst + 2, fenc(m.z)); atomicMax(dst + 3, fenc(m.w));
        }
    }
    __syncthreads();

    if (tid < D){
        unsigned e = lmax[tid];
        if (e) atomicMax(&xg[g0 * D + tid], e);
    } else {
        int f = tid - D;
        int g1 = g0 + 1;
        if (g1 < N_GRAPHS){
            unsigned e = lmax[D + f];
            if (e) atomicMax(&xg[g1 * D + f], e);
        }
    }
}

// ---------------- head: leaky(xg @ wg[:128] + bg) ----------------
__global__ __launch_bounds__(256) void k_final(const unsigned* __restrict__ xg_enc, const float* __restrict__ wg,
                                               const float* __restrict__ bg, float* __restrict__ out){
    __shared__ float xs[N_GRAPHS * D];
    int tid = threadIdx.x;
    for (int i = tid; i < N_GRAPHS * D; i += 256){
        unsigned e = xg_enc[i];
        xs[i] = (e == 0u) ? 0.f : fdec(e);
    }
    __syncthreads();
    int g = tid >> 4;
    int j0 = (tid & 15) * 8;
    float acc[8];
    #pragma unroll
    for (int j = 0; j < 8; j++) acc[j] = 0.f;
    for (int k = 0; k < D; k++){
        float xv = xs[g * D + k];
        const float* wr = &wg[(size_t)k * D + j0];
        #pragma unroll
        for (int j = 0; j < 8; j++) acc[j] = fmaf(xv, wr[j], acc[j]);
    }
    float* orow = &out[(size_t)N_NODES * D + g * D + j0];
    #pragma unroll
    for (int j = 0; j < 8; j++) orow[j] = leaky(acc[j] + bg[j0 + j]);
}

extern "C" void kernel_launch(void* const* d_in, const int* in_sizes, int n_in,
                              void* d_out, int out_size, void* d_ws, size_t ws_size,
                              hipStream_t stream){
    const float* x = (const float*)d_in[0];
    const int* eidx  = (const int*)d_in[1];   // harness converts integer inputs to int32
    const int* batch = (const int*)d_in[2];
    const float* w[4]  = {(const float*)d_in[4], (const float*)d_in[6], (const float*)d_in[8], (const float*)d_in[10]};
    const float* bb[4] = {(const float*)d_in[5], (const float*)d_in[7], (const float*)d_in[9], (const float*)d_in[11]};
    const float* wg = (const float*)d_in[12];
    const float* bg = (const float*)d_in[13];
    const int* esrc = eidx;
    const int* edst = eidx + N_EDGES;

    // workspace layout: base ~3.6 MB + hb0 12.8 MB (+ hb1 12.8 MB if ws allows ping-pong)
    char* ws = (char*)d_ws;
    int* deg    = (int*)ws;       ws += 50048 * 4;
    int* off    = (int*)ws;       ws += 50048 * 4;
    int* cursor = (int*)ws;       ws += 50048 * 4;
    int* perm   = (int*)ws;       ws += 50048 * 4;
    int* bsum   = (int*)ws;       ws += 256 * 4;
    int* bbase  = (int*)ws;       ws += 256 * 4;
    int* bins   = (int*)ws;       ws += 256 * 4;
    int* bincur = (int*)ws;       ws += 256 * 4;
    unsigned* xg_enc = (unsigned*)ws; ws += N_GRAPHS * D * 4;
    unsigned short* Wt = (unsigned short*)ws; ws += 4 * 2 * D * D * 2;  // 4 layers, [n][k] bf16
    unsigned short* csr16 = (unsigned short*)ws; ws += CSR_CAP * 2;
    unsigned short* hb0 = (unsigned short*)(((uintptr_t)ws + 255) & ~(uintptr_t)255);
    unsigned short* hb1 = hb0 + HB_ELEMS;
    size_t need_pp = (size_t)((char*)(hb1 + HB_ELEMS) - (char*)d_ws);
    int pp = (ws_size >= need_pp);     // ping-pong shadow if workspace allows (deterministic per run)
    float* h = (float*)d_out;          // f32 h lives in the output buffer (fully written by step 0)

    k_pre  <<<6250, 256, 0, stream>>>(x, hb0, w[0], w[1], w[2], w[3], Wt, deg, xg_enc, bins);
    k_hist <<<(N_EDGES / 4 + 255) / 256, 256, 0, stream>>>(edst, deg);
    k_scan1<<<SCAN_BLOCKS, 256, 0, stream>>>(deg, bsum);
    k_scan2<<<1, 256, 0, stream>>>(bsum, bbase);
    k_scan3<<<SCAN_BLOCKS, 256, 0, stream>>>(deg, bbase, off, cursor);
    k_fill <<<(N_EDGES / 4 + 255) / 256, 256, 0, stream>>>(esrc, edst, cursor, csr16);
    k_pad  <<<SCAN_BLOCKS, 256, 0, stream>>>(deg, off, csr16);
    k_dhist<<<SCAN_BLOCKS, 256, 0, stream>>>(deg, bins);
    k_dscan<<<1, 256, 0, stream>>>(bins, bincur);
    k_dscat<<<SCAN_BLOCKS, 256, 0, stream>>>(deg, bincur, perm);

    unsigned short* cur = hb0;
    unsigned short* nxt = pp ? hb1 : hb0;
    for (int s = 0; s < 4; s++){
        int wb = pp && (s < 3);        // ping-pong: write next shadow in-kernel (separate buffer)
        k_step<<<(N_NODES + 63) / 64, 512, 0, stream>>>(h, cur, csr16, deg, off, perm,
                                                        Wt + (size_t)s * 2 * D * D, bb[s], h, nxt,
                                                        s > 0, wb);
        if (!pp && s < 3)              // fallback: refresh single shadow in a separate launch
            k_cvt<<<6250, 256, 0, stream>>>(h, hb0);
        if (pp){ unsigned short* t = cur; cur = nxt; nxt = t; }
    }

    k_pool <<<(N_NODES + PBLK - 1) / PBLK, 256, 0, stream>>>(h, batch, xg_enc);
    k_final<<<1, 256, 0, stream>>>(xg_enc, wg, bg, (float*)d_out);
}

// Round 13
// 433.937 us; speedup vs baseline: 1.6672x; 1.0711x over previous
//
#include <hip/hip_runtime.h>
#include <stdint.h>
#include <math.h>

#define N_NODES 50000
#define N_EDGES 800000
#define D 128
#define N_GRAPHS 16
#define ZP 264         // LDS z-tile row pitch in bf16 elems (264*2B=528B = 132 floats -> 16B-aligned rows)
#define TN 32          // nodes per step-block
#define PBLK 128       // nodes per pool block
#define PSL 16         // nodes per pool slice
#define SCAN_BLOCKS 196
#define CSR_CAP 1150400 // sum of 8-padded degrees <= 800000 + 7*50000
#define HB_ELEMS ((size_t)N_NODES * D)

typedef __attribute__((ext_vector_type(8))) short bf16x8;   // 8 bf16 (4 VGPRs)
typedef __attribute__((ext_vector_type(4))) float f32x4;

__device__ __forceinline__ float leaky(float y){ return y > 0.f ? y : 0.01f * y; }

// monotonic float->uint encoding for atomic max; 0 = "empty" marker
__device__ __forceinline__ unsigned fenc(float f){
    unsigned u = __float_as_uint(f);
    return (f >= 0.f) ? (u | 0x80000000u) : ~u;
}
__device__ __forceinline__ float fdec(unsigned e){
    return (e & 0x80000000u) ? __uint_as_float(e & 0x7fffffffu) : __uint_as_float(~e);
}

// bf16 pack/unpack (round-to-nearest-even)
__device__ __forceinline__ unsigned short f2bf(float f){
    unsigned u = __float_as_uint(f);
    u += 0x7fffu + ((u >> 16) & 1u);
    return (unsigned short)(u >> 16);
}
__device__ __forceinline__ unsigned pk2(float lo, float hi){
    return (unsigned)f2bf(lo) | ((unsigned)f2bf(hi) << 16);
}
__device__ __forceinline__ void maxbf8(float a[8], uint4 v){
    a[0] = fmaxf(a[0], __uint_as_float(v.x << 16)); a[1] = fmaxf(a[1], __uint_as_float(v.x & 0xffff0000u));
    a[2] = fmaxf(a[2], __uint_as_float(v.y << 16)); a[3] = fmaxf(a[3], __uint_as_float(v.y & 0xffff0000u));
    a[4] = fmaxf(a[4], __uint_as_float(v.z << 16)); a[5] = fmaxf(a[5], __uint_as_float(v.z & 0xffff0000u));
    a[6] = fmaxf(a[6], __uint_as_float(v.w << 16)); a[7] = fmaxf(a[7], __uint_as_float(v.w & 0xffff0000u));
}
__device__ __forceinline__ float4 max4(float4 a, float4 b){
    float4 r;
    r.x = fmaxf(a.x, b.x); r.y = fmaxf(a.y, b.y);
    r.z = fmaxf(a.z, b.z); r.w = fmaxf(a.w, b.w);
    return r;
}

// ---------------- combined pre-pass: hb=bf16(x), Wt transpose, zero deg/xg/bins ----------------
__global__ __launch_bounds__(256) void k_pre(const float* __restrict__ x, unsigned short* __restrict__ hb,
                                             const float* __restrict__ w0, const float* __restrict__ w1,
                                             const float* __restrict__ w2, const float* __restrict__ w3,
                                             unsigned short* __restrict__ Wt,
                                             int* __restrict__ deg, unsigned* __restrict__ xg,
                                             int* __restrict__ bins){
    int id = blockIdx.x * 256 + threadIdx.x;
    if (id < N_NODES * D / 4){
        float4 v = ((const float4*)x)[id];
        uint2 r; r.x = pk2(v.x, v.y); r.y = pk2(v.z, v.w);
        ((uint2*)hb)[id] = r;
    }
    if (id < 4 * D * 2 * D){
        int layer = id >> 15;
        int rem = id & 32767;
        int n = rem >> 8;
        int k = rem & 255;
        const float* w = (layer == 0) ? w0 : (layer == 1) ? w1 : (layer == 2) ? w2 : w3;
        Wt[id] = f2bf(w[(size_t)k * D + n]);
    }
    if (id < 50048) deg[id] = 0;
    if (id < N_GRAPHS * D) xg[id] = 0u;
    if (id < 256) bins[id] = 0;
}

// ---------------- f32 -> bf16 shadow convert (fallback path) ----------------
__global__ __launch_bounds__(256) void k_cvt(const float* __restrict__ src, unsigned short* __restrict__ dst){
    int id = blockIdx.x * 256 + threadIdx.x;
    if (id < N_NODES * D / 4){
        float4 v = ((const float4*)src)[id];
        uint2 r; r.x = pk2(v.x, v.y); r.y = pk2(v.z, v.w);
        ((uint2*)dst)[id] = r;
    }
}

// ---------------- CSR build (int4 reads, ushort entries, 8-aligned 8-padded segments) ----------------
__global__ __launch_bounds__(256) void k_hist(const int* __restrict__ dst, int* __restrict__ deg){
    int e4 = blockIdx.x * 256 + threadIdx.x;
    if (e4 < N_EDGES / 4){
        int4 d = ((const int4*)dst)[e4];
        atomicAdd(&deg[d.x], 1); atomicAdd(&deg[d.y], 1);
        atomicAdd(&deg[d.z], 1); atomicAdd(&deg[d.w], 1);
    }
}

// padded block-sum for CSR offsets + LDS-aggregated degree histogram (fused)
__global__ __launch_bounds__(256) void k_scan1(const int* __restrict__ deg, int* __restrict__ bsum,
                                               int* __restrict__ bins){
    __shared__ int sh[256];
    __shared__ int lb[256];
    int t = threadIdx.x;
    lb[t] = 0;
    int i = blockIdx.x * 256 + t;
    int dv = (i < N_NODES) ? deg[i] : 0;
    sh[t] = (dv + 7) & ~7;               // 8-padded
    __syncthreads();
    if (i < N_NODES) atomicAdd(&lb[min(dv, 255)], 1);
    for (int s = 128; s > 0; s >>= 1){
        if (t < s) sh[t] += sh[t + s];
        __syncthreads();
    }
    if (t == 0) bsum[blockIdx.x] = sh[0];
    int c = lb[t];
    if (c > 0) atomicAdd(&bins[t], c);
}

// block-sum scan + degree-bin scan (fused, one block)
__global__ __launch_bounds__(256) void k_scan2(const int* __restrict__ bsum, int* __restrict__ bbase,
                                               const int* __restrict__ bins, int* __restrict__ bincur){
    __shared__ int sh[256];
    int t = threadIdx.x;
    int v = (t < SCAN_BLOCKS) ? bsum[t] : 0;
    sh[t] = v;
    __syncthreads();
    for (int d = 1; d < 256; d <<= 1){
        int tv = (t >= d) ? sh[t - d] : 0;
        __syncthreads();
        sh[t] += tv;
        __syncthreads();
    }
    if (t < SCAN_BLOCKS) bbase[t] = sh[t] - v;   // exclusive
    __syncthreads();
    int bv = bins[t];
    sh[t] = bv;
    __syncthreads();
    for (int d = 1; d < 256; d <<= 1){
        int tv = (t >= d) ? sh[t - d] : 0;
        __syncthreads();
        sh[t] += tv;
        __syncthreads();
    }
    bincur[t] = sh[t] - bv;   // exclusive base
}

__global__ __launch_bounds__(256) void k_scan3(const int* __restrict__ deg, const int* __restrict__ bbase,
                                               int* __restrict__ off, int* __restrict__ cursor){
    __shared__ int sh[256];
    int t = threadIdx.x;
    int i = blockIdx.x * 256 + t;
    int dv = (i < N_NODES) ? deg[i] : 0;
    int v = (dv + 7) & ~7;                        // 8-padded
    sh[t] = v;
    __syncthreads();
    for (int d = 1; d < 256; d <<= 1){
        int tv = (t >= d) ? sh[t - d] : 0;
        __syncthreads();
        sh[t] += tv;
        __syncthreads();
    }
    if (i < N_NODES){
        int e = bbase[blockIdx.x] + sh[t] - v;    // 8-aligned base
        off[i] = e;
        cursor[i] = e;
    }
}

__global__ __launch_bounds__(256) void k_fill(const int* __restrict__ src, const int* __restrict__ dst,
                                              int* __restrict__ cursor, unsigned short* __restrict__ csr16){
    int e4 = blockIdx.x * 256 + threadIdx.x;
    if (e4 < N_EDGES / 4){
        int4 d = ((const int4*)dst)[e4];
        int4 s = ((const int4*)src)[e4];
        int p;
        p = atomicAdd(&cursor[d.x], 1); csr16[p] = (unsigned short)s.x;
        p = atomicAdd(&cursor[d.y], 1); csr16[p] = (unsigned short)s.y;
        p = atomicAdd(&cursor[d.z], 1); csr16[p] = (unsigned short)s.z;
        p = atomicAdd(&cursor[d.w], 1); csr16[p] = (unsigned short)s.w;
    }
}

// pad each node's segment to a multiple of 8 by duplicating its first edge (max-invariant)
__global__ __launch_bounds__(256) void k_pad(const int* __restrict__ deg, const int* __restrict__ off,
                                             unsigned short* __restrict__ csr16){
    int i = blockIdx.x * 256 + threadIdx.x;
    if (i < N_NODES){
        int n = deg[i];
        if (n > 0){
            int base = off[i];
            unsigned short s0 = csr16[base];
            int n8 = (n + 7) & ~7;
            for (int j = n; j < n8; j++) csr16[base + j] = s0;
        }
    }
}

// LDS local ranks + one global atomic per populated bin per block; non-stable but valid permutation
__global__ __launch_bounds__(256) void k_dscat(const int* __restrict__ deg, int* __restrict__ bincur,
                                               int* __restrict__ perm){
    __shared__ int lb[256];
    __shared__ int gbase[256];
    int t = threadIdx.x;
    lb[t] = 0;
    __syncthreads();
    int i = blockIdx.x * 256 + t;
    int b = 0, lrank = 0;
    if (i < N_NODES){
        b = min(deg[i], 255);
        lrank = atomicAdd(&lb[b], 1);
    }
    __syncthreads();
    int c = lb[t];
    if (c > 0) gbase[t] = atomicAdd(&bincur[t], c);
    __syncthreads();
    if (i < N_NODES) perm[gbase[b] + lrank] = i;
}

// ---------------- fused step: 32-node tile, 1 node per 16-lane group, csr-prefetch gather ------
// 512 threads (8 waves). MFMA: wave w -> node-group (w&1)*16, out-quarter (w>>1)*32.
__global__ __launch_bounds__(512, 8) void k_step(const float* __restrict__ hin,
                                              const unsigned short* __restrict__ hb,
                                              const unsigned short* __restrict__ csr16,
                                              const int* __restrict__ deg, const int* __restrict__ off,
                                              const int* __restrict__ perm,
                                              const unsigned short* __restrict__ Wt, const float* __restrict__ b,
                                              float* __restrict__ hout, unsigned short* __restrict__ hbout,
                                              int add_skip, int write_hb){
    __shared__ unsigned short zt[TN * ZP];
    __shared__ int pn[TN];
    int tid = threadIdx.x;
    int nb = blockIdx.x * TN;
    int lane = tid & 63;
    int wv = tid >> 6;                    // 0..7

    if (tid < TN){
        int idx = nb + tid;
        pn[tid] = (idx < N_NODES) ? perm[idx] : -1;
    }
    __syncthreads();

    // stage h-half: 512 slots = 32 rows x 16 chunks (one shot)
    {
        int row = tid >> 4;               // 0..31
        int ch  = tid & 15;               // 16B chunk -> feats ch*8..+7
        int node = pn[row];
        uint4 v = make_uint4(0u, 0u, 0u, 0u);
        if (node >= 0) v = *(const uint4*)&hb[(size_t)node * D + ch * 8];
        *(uint4*)&zt[row * ZP + ch * 8] = v;
    }

    // gather-max: one node per 16-lane group, MLP=8, csr-prefetch, tail-free (8-padded CSR)
    {
        int group = tid >> 4;             // 0..31  == node row
        int chunk = tid & 15;             // feats chunk*8..+7
        int node = pn[group];
        int n = 0, base = 0;
        if (node >= 0){ n = deg[node]; base = off[node]; }
        const float NEG = -INFINITY;
        float a[8] = {NEG, NEG, NEG, NEG, NEG, NEG, NEG, NEG};
        int n8 = (n + 7) & ~7;            // 0 when n==0
        if (n8 > 0){
            uint4 ss = *(const uint4*)&csr16[base];       // 8 edge ids, 16B-aligned
            for (int i = 0; i < n8; i += 8){
                uint4 sc = ss;
                if (i + 8 < n8) ss = *(const uint4*)&csr16[base + i + 8];   // prefetch next ids
                int s0 = sc.x & 0xffff, s1 = sc.x >> 16;
                int s2 = sc.y & 0xffff, s3 = sc.y >> 16;
                int s4 = sc.z & 0xffff, s5 = sc.z >> 16;
                int s6 = sc.w & 0xffff, s7 = sc.w >> 16;
                uint4 v0 = *(const uint4*)&hb[(size_t)s0 * D + chunk * 8];
                uint4 v1 = *(const uint4*)&hb[(size_t)s1 * D + chunk * 8];
                uint4 v2 = *(const uint4*)&hb[(size_t)s2 * D + chunk * 8];
                uint4 v3 = *(const uint4*)&hb[(size_t)s3 * D + chunk * 8];
                uint4 v4 = *(const uint4*)&hb[(size_t)s4 * D + chunk * 8];
                uint4 v5 = *(const uint4*)&hb[(size_t)s5 * D + chunk * 8];
                uint4 v6 = *(const uint4*)&hb[(size_t)s6 * D + chunk * 8];
                uint4 v7 = *(const uint4*)&hb[(size_t)s7 * D + chunk * 8];
                maxbf8(a, v0); maxbf8(a, v1); maxbf8(a, v2); maxbf8(a, v3);
                maxbf8(a, v4); maxbf8(a, v5); maxbf8(a, v6); maxbf8(a, v7);
            }
        }
        uint4 r;
        if (n == 0){
            r = make_uint4(0u, 0u, 0u, 0u);
        } else {
            r.x = pk2(a[0], a[1]); r.y = pk2(a[2], a[3]);
            r.z = pk2(a[4], a[5]); r.w = pk2(a[6], a[7]);
        }
        *(uint4*)&zt[group * ZP + D + chunk * 8] = r;
    }
    __syncthreads();

    // MFMA: wave w -> nodes (w&1)*16..+15, out-quarter (w>>1)*32..+31
    int col = lane & 15;
    int quad = lane >> 4;
    int m0 = (wv & 1) * 16;
    int f0 = (wv >> 1) * 32;

    f32x4 acc[2];
    acc[0] = (f32x4){0.f, 0.f, 0.f, 0.f};
    acc[1] = (f32x4){0.f, 0.f, 0.f, 0.f};

    const unsigned short* zrow = &zt[(m0 + col) * ZP + quad * 8];
    const unsigned short* wrow = &Wt[(size_t)(f0 + col) * 256 + quad * 8];

    #pragma unroll
    for (int ks = 0; ks < 8; ks++){
        bf16x8 afrag = *(const bf16x8*)&zrow[ks * 32];
        #pragma unroll
        for (int nt = 0; nt < 2; nt++){
            bf16x8 bfrag = *(const bf16x8*)&wrow[nt * 16 * 256 + ks * 32];
            acc[nt] = __builtin_amdgcn_mfma_f32_16x16x32_bf16(afrag, bfrag, acc[nt], 0, 0, 0);
        }
    }

    __syncthreads();   // all waves done reading zt (A-frags)

    // write y = leaky(acc + b) into zt as f32 (pitch 132 floats = 528 B)
    float* zf = (float*)zt;
    #pragma unroll
    for (int nt = 0; nt < 2; nt++){
        int feat = f0 + nt * 16 + col;
        float bb_ = b[feat];
        #pragma unroll
        for (int r = 0; r < 4; r++){
            int row = m0 + quad * 4 + r;
            zf[row * 132 + feat] = leaky(acc[nt][r] + bb_);
        }
    }
    __syncthreads();

    // coalesced epilogue: 1024 float4 slots = 32 rows x 32 quads; 512 threads x 2
    #pragma unroll
    for (int j = 0; j < 2; j++){
        int idx = j * 512 + tid;
        int row = idx >> 5;               // 0..31
        int q = idx & 31;                 // feats 4q..4q+3
        int node = pn[row];
        if (node >= 0){
            float4 y = *(float4*)&zf[row * 132 + 4 * q];
            if (add_skip){
                float4 hv = *(const float4*)&hin[(size_t)node * D + 4 * q];
                y.x += hv.x; y.y += hv.y; y.z += hv.z; y.w += hv.w;
            }
            *(float4*)&hout[(size_t)node * D + 4 * q] = y;
            if (write_hb){
                ushort4 rb;
                rb.x = f2bf(y.x); rb.y = f2bf(y.y); rb.z = f2bf(y.z); rb.w = f2bf(y.w);
                *(ushort4*)&hbout[(size_t)node * D + 4 * q] = rb;
            }
        }
    }
}

// ---------------- global max-pool per graph (batch sorted, int32) ----------------
__global__ __launch_bounds__(256) void k_pool(const float* __restrict__ h, const int* __restrict__ batch,
                                              unsigned* __restrict__ xg){
    __shared__ unsigned lmax[2 * D];
    int tid = threadIdx.x;
    lmax[tid] = 0u;
    __syncthreads();

    int n0 = blockIdx.x * PBLK;
    int g0 = batch[n0];
    int q = tid & 31;
    int s = tid >> 5;
    int i0 = n0 + s * PSL;
    int i1 = min(i0 + PSL, N_NODES);

    if (i0 < N_NODES){
        const float NEG = -INFINITY;
        float4 m = make_float4(NEG, NEG, NEG, NEG);
        int curg = batch[i0];
        int i = i0;
        for (; i + 2 <= i1; i += 2){
            int ga = batch[i];
            int gb = batch[i + 1];
            float4 va = *(const float4*)&h[(size_t)i * D + 4 * q];
            float4 vb = *(const float4*)&h[(size_t)(i + 1) * D + 4 * q];
            if (ga != curg){
                int rel = curg - g0;
                unsigned* dst = (rel < 2) ? &lmax[rel * D + 4 * q] : &xg[curg * D + 4 * q];
                atomicMax(dst + 0, fenc(m.x)); atomicMax(dst + 1, fenc(m.y));
                atomicMax(dst + 2, fenc(m.z)); atomicMax(dst + 3, fenc(m.w));
                curg = ga; m = make_float4(NEG, NEG, NEG, NEG);
            }
            m = max4(m, va);
            if (gb != curg){
                int rel = curg - g0;
                unsigned* dst = (rel < 2) ? &lmax[rel * D + 4 * q] : &xg[curg * D + 4 * q];
                atomicMax(dst + 0, fenc(m.x)); atomicMax(dst + 1, fenc(m.y));
                atomicMax(dst + 2, fenc(m.z)); atomicMax(dst + 3, fenc(m.w));
                curg = gb; m = make_float4(NEG, NEG, NEG, NEG);
            }
            m = max4(m, vb);
        }
        if (i < i1){
            int ga = batch[i];
            float4 va = *(const float4*)&h[(size_t)i * D + 4 * q];
            if (ga != curg){
                int rel = curg - g0;
                unsigned* dst = (rel < 2) ? &lmax[rel * D + 4 * q] : &xg[curg * D + 4 * q];
                atomicMax(dst + 0, fenc(m.x)); atomicMax(dst + 1, fenc(m.y));
                atomicMax(dst + 2, fenc(m.z)); atomicMax(dst + 3, fenc(m.w));
                curg = ga; m = make_float4(NEG, NEG, NEG, NEG);
            }
            m = max4(m, va);
        }
        {
            int rel = curg - g0;
            unsigned* dst = (rel < 2) ? &lmax[rel * D + 4 * q] : &xg[curg * D + 4 * q];
            atomicMax(dst + 0, fenc(m.x)); atomicMax(dst + 1, fenc(m.y));
            atomicMax(dst + 2, fenc(m.z)); atomicMax(dst + 3, fenc(m.w));
        }
    }
    __syncthreads();

    if (tid < D){
        unsigned e = lmax[tid];
        if (e) atomicMax(&xg[g0 * D + tid], e);
    } else {
        int f = tid - D;
        int g1 = g0 + 1;
        if (g1 < N_GRAPHS){
            unsigned e = lmax[D + f];
            if (e) atomicMax(&xg[g1 * D + f], e);
        }
    }
}

// ---------------- head: leaky(xg @ wg[:128] + bg) ----------------
__global__ __launch_bounds__(256) void k_final(const unsigned* __restrict__ xg_enc, const float* __restrict__ wg,
                                               const float* __restrict__ bg, float* __restrict__ out){
    __shared__ float xs[N_GRAPHS * D];
    int tid = threadIdx.x;
    for (int i = tid; i < N_GRAPHS * D; i += 256){
        unsigned e = xg_enc[i];
        xs[i] = (e == 0u) ? 0.f : fdec(e);
    }
    __syncthreads();
    int g = tid >> 4;
    int j0 = (tid & 15) * 8;
    float acc[8];
    #pragma unroll
    for (int j = 0; j < 8; j++) acc[j] = 0.f;
    for (int k = 0; k < D; k++){
        float xv = xs[g * D + k];
        const float* wr = &wg[(size_t)k * D + j0];
        #pragma unroll
        for (int j = 0; j < 8; j++) acc[j] = fmaf(xv, wr[j], acc[j]);
    }
    float* orow = &out[(size_t)N_NODES * D + g * D + j0];
    #pragma unroll
    for (int j = 0; j < 8; j++) orow[j] = leaky(acc[j] + bg[j0 + j]);
}

extern "C" void kernel_launch(void* const* d_in, const int* in_sizes, int n_in,
                              void* d_out, int out_size, void* d_ws, size_t ws_size,
                              hipStream_t stream){
    const float* x = (const float*)d_in[0];
    const int* eidx  = (const int*)d_in[1];   // harness converts integer inputs to int32
    const int* batch = (const int*)d_in[2];
    const float* w[4]  = {(const float*)d_in[4], (const float*)d_in[6], (const float*)d_in[8], (const float*)d_in[10]};
    const float* bb[4] = {(const float*)d_in[5], (const float*)d_in[7], (const float*)d_in[9], (const float*)d_in[11]};
    const float* wg = (const float*)d_in[12];
    const float* bg = (const float*)d_in[13];
    const int* esrc = eidx;
    const int* edst = eidx + N_EDGES;

    // workspace layout: base ~3.6 MB + hb0 12.8 MB (+ hb1 12.8 MB if ws allows ping-pong)
    char* ws = (char*)d_ws;
    int* deg    = (int*)ws;       ws += 50048 * 4;
    int* off    = (int*)ws;       ws += 50048 * 4;
    int* cursor = (int*)ws;       ws += 50048 * 4;
    int* perm   = (int*)ws;       ws += 50048 * 4;
    int* bsum   = (int*)ws;       ws += 256 * 4;
    int* bbase  = (int*)ws;       ws += 256 * 4;
    int* bins   = (int*)ws;       ws += 256 * 4;
    int* bincur = (int*)ws;       ws += 256 * 4;
    unsigned* xg_enc = (unsigned*)ws; ws += N_GRAPHS * D * 4;
    unsigned short* Wt = (unsigned short*)ws; ws += 4 * 2 * D * D * 2;  // 4 layers, [n][k] bf16
    unsigned short* csr16 = (unsigned short*)ws; ws += CSR_CAP * 2;
    unsigned short* hb0 = (unsigned short*)(((uintptr_t)ws + 255) & ~(uintptr_t)255);
    unsigned short* hb1 = hb0 + HB_ELEMS;
    size_t need_pp = (size_t)((char*)(hb1 + HB_ELEMS) - (char*)d_ws);
    int pp = (ws_size >= need_pp);     // ping-pong shadow if workspace allows (deterministic per run)
    float* h = (float*)d_out;          // f32 h lives in the output buffer (fully written by step 0)

    k_pre  <<<6250, 256, 0, stream>>>(x, hb0, w[0], w[1], w[2], w[3], Wt, deg, xg_enc, bins);
    k_hist <<<(N_EDGES / 4 + 255) / 256, 256, 0, stream>>>(edst, deg);
    k_scan1<<<SCAN_BLOCKS, 256, 0, stream>>>(deg, bsum, bins);
    k_scan2<<<1, 256, 0, stream>>>(bsum, bbase, bins, bincur);
    k_scan3<<<SCAN_BLOCKS, 256, 0, stream>>>(deg, bbase, off, cursor);
    k_fill <<<(N_EDGES / 4 + 255) / 256, 256, 0, stream>>>(esrc, edst, cursor, csr16);
    k_pad  <<<SCAN_BLOCKS, 256, 0, stream>>>(deg, off, csr16);
    k_dscat<<<SCAN_BLOCKS, 256, 0, stream>>>(deg, bincur, perm);

    unsigned short* cur = hb0;
    unsigned short* nxt = pp ? hb1 : hb0;
    for (int s = 0; s < 4; s++){
        int wb = pp && (s < 3);        // ping-pong: write next shadow in-kernel (separate buffer)
        k_step<<<(N_NODES + TN - 1) / TN, 512, 0, stream>>>(h, cur, csr16, deg, off, perm,
                                                        Wt + (size_t)s * 2 * D * D, bb[s], h, nxt,
                                                        s > 0, wb);
        if (!pp && s < 3)              // fallback: refresh single shadow in a separate launch
            k_cvt<<<6250, 256, 0, stream>>>(h, hb0);
        if (pp){ unsigned short* t = cur; cur = nxt; nxt = t; }
    }

    k_pool <<<(N_NODES + PBLK - 1) / PBLK, 256, 0, stream>>>(h, batch, xg_enc);
    k_final<<<1, 256, 0, stream>>>(xg_enc, wg, bg, (float*)d_out);
}